// Round 7
// baseline (1333.179 us; speedup 1.0000x reference)
//
#include <hip/hip_runtime.h>

// CRF Viterbi decode (B=512, T=512, S=64).
// R6: 2 waves/block (128 thr), one batch/block. Wave w in {0,1} owns prevs
// [32w, 32w+32); lane n = next-tag everywhere. Phase 1: 32 in-register
// readlane gathers + 32 adds + balanced carry-index tree (depth 5, strict >,
// left-on-tie; slice ordered ascending => exact jnp first-argmax). Exchange:
// ONE ds_write_b64 into i&1 double-buffered partials, ONE 2-wave barrier,
// ONE ds_read_b64 of partner partial, one ordered 2-way merge (wave0 slice
// = left operand). Both waves compute the identical new fv in registers --
// no fv LDS round-trip, no second barrier. Emissions+masks prefetched
// depth-2 (never on the chain). Backpointers: every lane computes its own
// bptr[i][n]; wave 0 packs 4 steps/dword into LDS. Backtrace: wave 0
// readlane chain (validated bit-exact R1-R5).
// Output: out[0..B) = path_score, out[B + b*(T-1) + t] = (float)tag.

constexpr int Bz = 512;
constexpr int Tz = 512;
constexpr int Sz = 64;
constexpr float NEGINF = -10000.0f;

__device__ __forceinline__ float rlf(float x, int lane) {
    return __int_as_float(__builtin_amdgcn_readlane(__float_as_int(x), lane));
}

__global__ __launch_bounds__(128)
void crf_viterbi_kernel(const float* __restrict__ logits,
                        const float* __restrict__ masks,
                        const float* __restrict__ trans,
                        float* __restrict__ out)
{
    const int n  = threadIdx.x & 63;   // lane id = next-tag
    const int w  = threadIdx.x >> 6;   // wave id 0..1, owns prevs [32w,32w+32)
    const int b  = blockIdx.x;
    const int pb = 32 * w;

    __shared__ unsigned bp[128 * 64];  // packed backpointers, 32 KB
    __shared__ int2 pvi[2][2][64];     // [buf][wave][n] partial {val bits, prev idx}
    __shared__ float ys[Tz - 1];       // emitted tags (backtrace)

    // transitions slice: tr[jj] = trans[n][32w + jj]
    float tr[32];
    {
        const float4* tr4 = reinterpret_cast<const float4*>(trans + n * 64 + pb);
        #pragma unroll
        for (int k = 0; k < 8; ++k) {
            float4 t = tr4[k];
            tr[4 * k + 0] = t.x; tr[4 * k + 1] = t.y;
            tr[4 * k + 2] = t.z; tr[4 * k + 3] = t.w;
        }
    }

    // fv replicated in both waves' registers, lane n = fv[n]
    float fv = (n == 0) ? 0.0f : NEGINF;

    const float* lgbase = logits + (size_t)b * Tz * Sz;
    const float* mkbase = masks + (size_t)b * Tz;

    // depth-2 prefetch: lg0/mk0 for step i, lg1/mk1 for step i+1
    float lg0 = lgbase[1 * Sz + n], lg1 = lgbase[2 * Sz + n];
    float mk0 = mkbase[1],          mk1 = mkbase[2];

    unsigned pk = 0;
    float psc = 0.0f;

    #pragma unroll 2
    for (int i = 0; i < Tz - 1; ++i) {
        // ---- phase 1: this wave's 32-prev slice, all 64 next-tags ----
        float v[32];
        #pragma unroll
        for (int jj = 0; jj < 32; ++jj)
            v[jj] = rlf(fv, pb + jj) + tr[jj];

        // balanced carry-index tree, depth 5 (strict >, left keeps ties)
        float mv[16]; int mi[16];
        #pragma unroll
        for (int c = 0; c < 16; ++c) {
            bool g = v[2 * c + 1] > v[2 * c];
            mv[c] = g ? v[2 * c + 1] : v[2 * c];
            mi[c] = g ? (2 * c + 1) : (2 * c);
        }
        #pragma unroll
        for (int st = 1; st < 16; st <<= 1) {
            #pragma unroll
            for (int c = 0; c < 16; c += 2 * st) {
                bool g = mv[c + st] > mv[c];
                mv[c] = g ? mv[c + st] : mv[c];
                mi[c] = g ? mi[c + st] : mi[c];
            }
        }

        pvi[i & 1][w][n] = make_int2(__float_as_int(mv[0]), pb + mi[0]);
        __syncthreads();                  // the only barrier (2-wave rendezvous)

        int2 o = pvi[i & 1][1 - w][n];    // partner's partial
        float ov = __int_as_float(o.x);

        // ordered merge: wave0 slice (prevs 0..31) is the LEFT operand
        float lv, rv; int li_, ri_;
        if (w == 0) { lv = mv[0]; li_ = pb + mi[0]; rv = ov;    ri_ = o.y; }
        else        { lv = ov;    li_ = o.y;        rv = mv[0]; ri_ = pb + mi[0]; }
        bool g = rv > lv;
        float m = g ? rv : lv;
        int  gi = g ? ri_ : li_;

        if (i == Tz - 2) psc = m;         // vmaxs[-1] pre-feat (lane 63)

        pk |= ((unsigned)gi) << (8 * (i & 3));
        if ((i & 3) == 3) {
            if (w == 0) bp[(i >> 2) * 64 + n] = pk;
            pk = 0;
        }

        fv = m + lg0 * mk0;               // mask multiplies emission only

        // rotate prefetch (off-chain)
        lg0 = lg1; mk0 = mk1;
        int tn = (i + 3 < Tz) ? (i + 3) : (Tz - 1);
        lg1 = lgbase[tn * Sz + n];
        mk1 = mkbase[tn];
    }

    if (w == 0) {
        bp[127 * 64 + n] = pk;            // flush steps 508..510
        if (n == 63) out[b] = psc;        // path_score = vmaxs[-1][:,63]
    }
    __syncthreads();

    // ---- backtrace (wave 0 only; validated readlane chain) ----
    if (w == 0) {
        unsigned wcur = bp[127 * 64 + n];
        int w127_63 = __builtin_amdgcn_readlane((int)wcur, 63);
        int tag = (w127_63 >> 16) & 255;  // t0 = bptrs[510][63]

        for (int gg = 127; gg >= 0; --gg) {
            unsigned wnext = (gg > 0) ? bp[(gg - 1) * 64 + n] : 0u;  // prefetch
            int smax = (gg == 127) ? 2 : 3;
            for (int s = smax; s >= 0; --s) {
                int idx = 4 * gg + s;
                if (n == 0) ys[idx] = (float)tag;   // emit BEFORE following ptr
                int wd = __builtin_amdgcn_readlane((int)wcur, tag);
                tag = (wd >> (8 * s)) & 255;
            }
            wcur = wnext;
        }
    }
    __syncthreads();

    float* outseq = out + Bz + (size_t)b * (Tz - 1);
    for (int k = threadIdx.x; k < Tz - 1; k += 128) outseq[k] = ys[k];
}

extern "C" void kernel_launch(void* const* d_in, const int* in_sizes, int n_in,
                              void* d_out, int out_size, void* d_ws, size_t ws_size,
                              hipStream_t stream) {
    const float* logits = (const float*)d_in[0];
    const float* masks  = (const float*)d_in[1];
    const float* trans  = (const float*)d_in[2];
    float* out = (float*)d_out;
    (void)in_sizes; (void)n_in; (void)out_size; (void)d_ws; (void)ws_size;

    crf_viterbi_kernel<<<dim3(Bz), dim3(128), 0, stream>>>(logits, masks, trans, out);
}

// Round 8
// 541.165 us; speedup vs baseline: 2.4635x; 2.4635x over previous
//
#include <hip/hip_runtime.h>

// CRF Viterbi decode (B=512, T=512, S=64).
// R7: 4 waves/block (256 thr), one batch/block. NO v_readlane in the hot
// loop (R4-R6 regression root-cause: runtime lane index -> waterfall loop).
// Merged fv lives lane-wise (lane n = fv[n]) in EVERY wave. Phase 1: wave w
// gathers fv[16w..16w+16) via 16 ds_bpermute broadcasts (per-lane-index HW
// permute, never waterfalls; index regs built once), adds trans slice,
// carry-index ordered tree depth 4 (strict >, left-on-tie = exact jnp
// first-argmax), publishes {val,idx} as one ds_write_b64 (i&1 double buffer).
// ONE barrier. Then ALL waves merge the 4 partials (4x ds_read_b64, 2-way
// bank alias = free; ordered merge) -> new fv in-register everywhere; no
// second barrier, no fv LDS round-trip. Emissions/masks prefetched depth-2.
// Backpointers packed 4 tags/dword (wave 0 writes); backtrace = wave 0
// readlane chain (validated bit-exact R1-R6).
// Output: out[0..B) = path_score, out[B + b*(T-1) + t] = (float)tag.

constexpr int Bz = 512;
constexpr int Tz = 512;
constexpr int Sz = 64;
constexpr float NEGINF = -10000.0f;

__global__ __launch_bounds__(256)
void crf_viterbi_kernel(const float* __restrict__ logits,
                        const float* __restrict__ masks,
                        const float* __restrict__ trans,
                        float* __restrict__ out)
{
    const int n = threadIdx.x & 63;    // lane id = next-tag
    const int w = __builtin_amdgcn_readfirstlane(threadIdx.x >> 6); // uniform wave id
    const int b = blockIdx.x;
    const int pb = 16 * w;             // first prev this wave owns (SGPR expr)

    __shared__ unsigned bp[128 * 64];  // packed backpointers, 32 KB
    __shared__ int2 pvi[2][4][64];     // [buf][wave][n] partial {val bits, prev idx}
    __shared__ float ys[Tz - 1];       // emitted tags (backtrace)

    // bpermute byte-index registers (lane-invariant), built once
    int bpi[16];
    #pragma unroll
    for (int jj = 0; jj < 16; ++jj) bpi[jj] = (pb + jj) * 4;

    // transitions slice: tr[jj] = trans[n][pb + jj]
    float tr[16];
    {
        const float4* tr4 = reinterpret_cast<const float4*>(trans + n * 64 + pb);
        #pragma unroll
        for (int k = 0; k < 4; ++k) {
            float4 t = tr4[k];
            tr[4 * k + 0] = t.x; tr[4 * k + 1] = t.y;
            tr[4 * k + 2] = t.z; tr[4 * k + 3] = t.w;
        }
    }

    // merged fv replicated in every wave: lane n = fv[n]
    float fv = (n == 0) ? 0.0f : NEGINF;

    const float* lgbase = logits + (size_t)b * Tz * Sz;
    const float* mkbase = masks + (size_t)b * Tz;

    // depth-2 prefetch: lg0/mk0 for step i, lg1/mk1 for step i+1
    float lg0 = lgbase[1 * Sz + n], lg1 = lgbase[2 * Sz + n];
    float mk0 = mkbase[1],          mk1 = mkbase[2];

    unsigned pk = 0;
    float psc = 0.0f;

    #pragma unroll 2
    for (int i = 0; i < Tz - 1; ++i) {
        // ---- phase 1: gather this wave's 16-prev slice via bpermute ----
        float v[16];
        #pragma unroll
        for (int jj = 0; jj < 16; ++jj)
            v[jj] = __int_as_float(
                        __builtin_amdgcn_ds_bpermute(bpi[jj], __float_as_int(fv)))
                    + tr[jj];

        // carry-index ordered tree, depth 4 (strict >, left keeps ties)
        float mv[8]; int mi[8];
        #pragma unroll
        for (int c = 0; c < 8; ++c) {
            bool g = v[2 * c + 1] > v[2 * c];
            mv[c] = g ? v[2 * c + 1] : v[2 * c];
            mi[c] = g ? (2 * c + 1) : (2 * c);
        }
        #pragma unroll
        for (int st = 1; st < 8; st <<= 1) {
            #pragma unroll
            for (int c = 0; c < 8; c += 2 * st) {
                bool g = mv[c + st] > mv[c];
                mv[c] = g ? mv[c + st] : mv[c];
                mi[c] = g ? mi[c + st] : mi[c];
            }
        }

        pvi[i & 1][w][n] = make_int2(__float_as_int(mv[0]), pb + mi[0]);
        __syncthreads();                  // the ONLY barrier per step

        // ---- phase 2: ALL waves merge the 4 partials (ordered, q asc) ----
        float cv[4]; int ci[4];
        #pragma unroll
        for (int q = 0; q < 4; ++q) {
            int2 p = pvi[i & 1][q][n];
            cv[q] = __int_as_float(p.x);
            ci[q] = p.y;
        }
        bool g1 = cv[1] > cv[0];
        float m01 = g1 ? cv[1] : cv[0];  int k01 = g1 ? ci[1] : ci[0];
        bool g3 = cv[3] > cv[2];
        float m23 = g3 ? cv[3] : cv[2];  int k23 = g3 ? ci[3] : ci[2];
        bool gm = m23 > m01;
        float m  = gm ? m23 : m01;
        int   gi = gm ? k23 : k01;

        if (i == Tz - 2) psc = m;         // vmaxs[-1] pre-feat (lane 63)

        pk |= ((unsigned)gi) << (8 * (i & 3));
        if ((i & 3) == 3) {
            if (w == 0) bp[(i >> 2) * 64 + n] = pk;
            pk = 0;
        }

        fv = m + lg0 * mk0;               // mask multiplies emission only

        // rotate prefetch (off-chain)
        lg0 = lg1; mk0 = mk1;
        int tn = (i + 3 < Tz) ? (i + 3) : (Tz - 1);
        lg1 = lgbase[tn * Sz + n];
        mk1 = mkbase[tn];
    }

    if (w == 0) {
        bp[127 * 64 + n] = pk;            // flush steps 508..510
        if (n == 63) out[b] = psc;        // path_score = vmaxs[-1][:,63]
    }
    __syncthreads();

    // ---- backtrace (wave 0 only; validated readlane chain) ----
    if (w == 0) {
        unsigned wcur = bp[127 * 64 + n];
        int w127_63 = __builtin_amdgcn_readlane((int)wcur, 63);
        int tag = (w127_63 >> 16) & 255;  // t0 = bptrs[510][63]

        for (int g = 127; g >= 0; --g) {
            unsigned wnext = (g > 0) ? bp[(g - 1) * 64 + n] : 0u;  // prefetch
            int smax = (g == 127) ? 2 : 3;
            for (int s = smax; s >= 0; --s) {
                int idx = 4 * g + s;
                if (n == 0) ys[idx] = (float)tag;   // emit BEFORE following ptr
                int wd = __builtin_amdgcn_readlane((int)wcur, tag);
                tag = (wd >> (8 * s)) & 255;
            }
            wcur = wnext;
        }
    }
    __syncthreads();

    float* outseq = out + Bz + (size_t)b * (Tz - 1);
    for (int k = threadIdx.x; k < Tz - 1; k += 256) outseq[k] = ys[k];
}

extern "C" void kernel_launch(void* const* d_in, const int* in_sizes, int n_in,
                              void* d_out, int out_size, void* d_ws, size_t ws_size,
                              hipStream_t stream) {
    const float* logits = (const float*)d_in[0];
    const float* masks  = (const float*)d_in[1];
    const float* trans  = (const float*)d_in[2];
    float* out = (float*)d_out;
    (void)in_sizes; (void)n_in; (void)out_size; (void)d_ws; (void)ws_size;

    crf_viterbi_kernel<<<dim3(Bz), dim3(256), 0, stream>>>(logits, masks, trans, out);
}

// Round 9
// 335.286 us; speedup vs baseline: 3.9762x; 1.6140x over previous
//
#include <hip/hip_runtime.h>

// CRF Viterbi decode (B=512, T=512, S=64).
// R8: 4 waves/block (256 thr), one batch/block, XOR-SWAPPED TAG SPACES.
// Wave w operates in tag space tg = n ^ 16w: lane n holds fv[tg]. Its
// 16-prev slice fv[16w..16w+16) is then lanes 0..15 of its own fv copy ->
// LITERAL-index v_readlane (no waterfall, no LDS on the gather). Phase 1:
// 16 readlane+add, carry-index ordered tree depth 4 (strict >, left-on-tie
// = exact jnp first-argmax), one ds_write_b64 partial into i&1 double
// buffer. ONE barrier. Phase 2: every wave reads the 4 partials at [q][tg]
// (ascending q = ascending prev range), ordered merge -> new fv in its own
// registers/space; no second barrier, no fv LDS round-trip. Emissions and
// masks prefetched in GROUPS of 4 steps, pipelined 2 groups ahead, so the
// pre-barrier vmcnt drain amortizes 4x. Wave 0 = identity space: writes
// packed backpointers (4 tags/dword), path_score, runs the validated
// readlane backtrace chain.
// Output: out[0..B) = path_score, out[B + b*(T-1) + t] = (float)tag.

constexpr int Bz = 512;
constexpr int Tz = 512;
constexpr int Sz = 64;
constexpr float NEGINF = -10000.0f;

__device__ __forceinline__ float rlf(float x, int lane) {
    return __int_as_float(__builtin_amdgcn_readlane(__float_as_int(x), lane));
}

__global__ __launch_bounds__(256)
void crf_viterbi_kernel(const float* __restrict__ logits,
                        const float* __restrict__ masks,
                        const float* __restrict__ trans,
                        float* __restrict__ out)
{
    const int n  = threadIdx.x & 63;                                  // lane id
    const int w  = __builtin_amdgcn_readfirstlane(threadIdx.x >> 6);  // uniform wave id
    const int b  = blockIdx.x;
    const int pb = 16 * w;            // SGPR: first prev of this wave's slice
    const int tg = n ^ pb;            // this lane's tag in wave-w swapped space

    __shared__ unsigned bp[128 * 64];   // packed backpointers, 32 KB
    __shared__ int2 pvi[2][4][64];      // [buf][wave][tag] partial {val bits, prev}
    __shared__ float ys[Tz - 1];        // emitted tags (backtrace)

    // transitions slice: tr[j] = trans[tg][pb + j]
    float tr[16];
    {
        const float4* tr4 = reinterpret_cast<const float4*>(trans + tg * 64 + pb);
        #pragma unroll
        for (int k = 0; k < 4; ++k) {
            float4 t = tr4[k];
            tr[4 * k + 0] = t.x; tr[4 * k + 1] = t.y;
            tr[4 * k + 2] = t.z; tr[4 * k + 3] = t.w;
        }
    }

    // fv in swapped layout: lane n holds fv[tg]
    float fv = (tg == 0) ? 0.0f : NEGINF;

    const float* lgbase = logits + (size_t)b * Tz * Sz;
    const float* mkbase = masks + (size_t)b * Tz;

    // group-of-4 software-pipelined prefetch (2 groups deep):
    // lgc/mkc = rows for current group, lgn/mkn = rows for next group.
    float lgc[4], lgn[4], mkc[4], mkn[4];
    #pragma unroll
    for (int k = 0; k < 4; ++k) {
        lgc[k] = lgbase[(1 + k) * Sz + tg];
        mkc[k] = mkbase[1 + k];
        lgn[k] = lgbase[(5 + k) * Sz + tg];
        mkn[k] = mkbase[5 + k];
    }

    unsigned pk = 0;
    float psc = 0.0f;

    // ---- one Viterbi step (compile-time k => literal buf, literal lanes) ----
    auto step = [&](int k, float lg, float mk) {
        const int buf = k & 1;
        // phase 1: gather own slice via LITERAL-lane readlanes
        float v[16];
        #pragma unroll
        for (int j = 0; j < 16; ++j)
            v[j] = rlf(fv, j) + tr[j];

        // carry-index ordered tree, depth 4 (strict >, left keeps ties)
        float mv[8]; int mi[8];
        #pragma unroll
        for (int c = 0; c < 8; ++c) {
            bool g = v[2 * c + 1] > v[2 * c];
            mv[c] = g ? v[2 * c + 1] : v[2 * c];
            mi[c] = g ? (2 * c + 1) : (2 * c);
        }
        #pragma unroll
        for (int st = 1; st < 8; st <<= 1) {
            #pragma unroll
            for (int c = 0; c < 8; c += 2 * st) {
                bool g = mv[c + st] > mv[c];
                mv[c] = g ? mv[c + st] : mv[c];
                mi[c] = g ? mi[c + st] : mi[c];
            }
        }
        pvi[buf][w][tg] = make_int2(__float_as_int(mv[0]), pb + mi[0]);

        __syncthreads();                 // the ONLY barrier per step

        // phase 2: merge 4 partials for tag tg (ascending q, left-on-tie)
        int2 p0 = pvi[buf][0][tg], p1 = pvi[buf][1][tg];
        int2 p2 = pvi[buf][2][tg], p3 = pvi[buf][3][tg];
        float c0 = __int_as_float(p0.x), c1 = __int_as_float(p1.x);
        float c2 = __int_as_float(p2.x), c3 = __int_as_float(p3.x);
        bool g1 = c1 > c0;  float m01 = g1 ? c1 : c0;  int k01 = g1 ? p1.y : p0.y;
        bool g3 = c3 > c2;  float m23 = g3 ? c3 : c2;  int k23 = g3 ? p3.y : p2.y;
        bool gm = m23 > m01;
        float m  = gm ? m23 : m01;
        int   gi = gm ? k23 : k01;

        pk |= ((unsigned)gi) << (8 * k);     // wave0: tg==n, others harmless
        fv = m + lg * mk;                    // mask multiplies emission only
        return m;                            // pre-feat max (for path_score)
    };

    // main: groups g = 0..126 cover steps i = 4g+k (i <= 507)
    for (int g = 0; g < 127; ++g) {
        step(0, lgc[0], mkc[0]);
        step(1, lgc[1], mkc[1]);
        step(2, lgc[2], mkc[2]);
        step(3, lgc[3], mkc[3]);

        if (w == 0) bp[g * 64 + n] = pk;     // identity space: tg == n
        pk = 0;

        // rotate prefetch; issue loads for group g+2 (rows 4g+9 .. 4g+12)
        #pragma unroll
        for (int k = 0; k < 4; ++k) { lgc[k] = lgn[k]; mkc[k] = mkn[k]; }
        #pragma unroll
        for (int k = 0; k < 4; ++k) {
            int t = 4 * g + 9 + k;
            t = (t < Tz) ? t : (Tz - 1);
            lgn[k] = lgbase[t * Sz + tg];
            mkn[k] = mkbase[t];
        }
    }

    // tail: steps 508, 509, 510 (group 127, k = 0..2)
    step(0, lgc[0], mkc[0]);
    step(1, lgc[1], mkc[1]);
    float mlast = step(2, lgc[2], mkc[2]);
    psc = mlast;                             // vmaxs[-1] pre-feat

    if (w == 0) {
        bp[127 * 64 + n] = pk;               // flush steps 508..510
        if (n == 63) out[b] = psc;           // path_score = vmaxs[-1][:,63]
    }
    __syncthreads();

    // ---- backtrace (wave 0 only; validated readlane chain) ----
    if (w == 0) {
        unsigned wcur = bp[127 * 64 + n];
        int w127_63 = __builtin_amdgcn_readlane((int)wcur, 63);
        int tag = (w127_63 >> 16) & 255;     // t0 = bptrs[510][63]

        for (int g = 127; g >= 0; --g) {
            unsigned wnext = (g > 0) ? bp[(g - 1) * 64 + n] : 0u;  // prefetch
            int smax = (g == 127) ? 2 : 3;
            for (int s = smax; s >= 0; --s) {
                int idx = 4 * g + s;
                if (n == 0) ys[idx] = (float)tag;   // emit BEFORE following ptr
                int wd = __builtin_amdgcn_readlane((int)wcur, tag);
                tag = (wd >> (8 * s)) & 255;
            }
            wcur = wnext;
        }
    }
    __syncthreads();

    float* outseq = out + Bz + (size_t)b * (Tz - 1);
    for (int k = threadIdx.x; k < Tz - 1; k += 256) outseq[k] = ys[k];
}

extern "C" void kernel_launch(void* const* d_in, const int* in_sizes, int n_in,
                              void* d_out, int out_size, void* d_ws, size_t ws_size,
                              hipStream_t stream) {
    const float* logits = (const float*)d_in[0];
    const float* masks  = (const float*)d_in[1];
    const float* trans  = (const float*)d_in[2];
    float* out = (float*)d_out;
    (void)in_sizes; (void)n_in; (void)out_size; (void)d_ws; (void)ws_size;

    crf_viterbi_kernel<<<dim3(Bz), dim3(256), 0, stream>>>(logits, masks, trans, out);
}

// Round 10
// 334.599 us; speedup vs baseline: 3.9844x; 1.0021x over previous
//
#include <hip/hip_runtime.h>

// CRF Viterbi decode (B=512, T=512, S=64).
// R9 = R8 (xor-swapped tag spaces, literal readlanes, 1 exchange/step) plus:
//  (1) hand-rolled barrier: s_waitcnt lgkmcnt(0) + s_barrier via inline asm.
//      The compiler's __syncthreads emits s_waitcnt vmcnt(0) before s_barrier,
//      which force-drains the emission/mask prefetch global loads onto the
//      synchronized critical path every step. We only need our ds_write
//      visible -> wait lgkmcnt only; global loads stay in flight (they land
//      in per-lane registers, no cross-wave visibility required).
//  (2) SoA partials (pval/pidx, b32) -- kills R8's 2.6M b64 bank conflicts.
// Wave w operates in tag space tg = n ^ 16w (lane n holds fv[tg]); its
// 16-prev slice fv[16w..16w+16) sits in lanes 0..15 of its own fv copy ->
// literal-index v_readlane (no waterfall). Carry-index ordered trees with
// strict >, left-on-tie everywhere = exact jnp first-argmax. Wave 0 is
// identity space: packs backpointers 4 tags/dword, runs validated backtrace.
// Output: out[0..B) = path_score, out[B + b*(T-1) + t] = (float)tag.

constexpr int Bz = 512;
constexpr int Tz = 512;
constexpr int Sz = 64;
constexpr float NEGINF = -10000.0f;

__device__ __forceinline__ float rlf(float x, int lane) {
    return __int_as_float(__builtin_amdgcn_readlane(__float_as_int(x), lane));
}

// Workgroup barrier that waits only on LDS ops (lgkmcnt), NOT vmcnt:
// keeps prefetch global loads in flight across the rendezvous.
__device__ __forceinline__ void lds_barrier() {
    asm volatile("s_waitcnt lgkmcnt(0)\n\ts_barrier" ::: "memory");
}

__global__ __launch_bounds__(256)
void crf_viterbi_kernel(const float* __restrict__ logits,
                        const float* __restrict__ masks,
                        const float* __restrict__ trans,
                        float* __restrict__ out)
{
    const int n  = threadIdx.x & 63;                                  // lane id
    const int w  = __builtin_amdgcn_readfirstlane(threadIdx.x >> 6);  // uniform wave id
    const int b  = blockIdx.x;
    const int pb = 16 * w;            // SGPR: first prev of this wave's slice
    const int tg = n ^ pb;            // this lane's tag in wave-w swapped space

    __shared__ unsigned bp[128 * 64];   // packed backpointers, 32 KB
    __shared__ float pval[2][4][64];    // [buf][wave][tag] partial value
    __shared__ int   pidx[2][4][64];    // [buf][wave][tag] partial argmax (prev)
    __shared__ float ys[Tz - 1];        // emitted tags (backtrace)

    // transitions slice: tr[j] = trans[tg][pb + j]
    float tr[16];
    {
        const float4* tr4 = reinterpret_cast<const float4*>(trans + tg * 64 + pb);
        #pragma unroll
        for (int k = 0; k < 4; ++k) {
            float4 t = tr4[k];
            tr[4 * k + 0] = t.x; tr[4 * k + 1] = t.y;
            tr[4 * k + 2] = t.z; tr[4 * k + 3] = t.w;
        }
    }

    // fv in swapped layout: lane n holds fv[tg]
    float fv = (tg == 0) ? 0.0f : NEGINF;

    const float* lgbase = logits + (size_t)b * Tz * Sz;
    const float* mkbase = masks + (size_t)b * Tz;

    // group-of-4 software-pipelined prefetch (2 groups deep)
    float lgc[4], lgn[4], mkc[4], mkn[4];
    #pragma unroll
    for (int k = 0; k < 4; ++k) {
        lgc[k] = lgbase[(1 + k) * Sz + tg];
        mkc[k] = mkbase[1 + k];
        lgn[k] = lgbase[(5 + k) * Sz + tg];
        mkn[k] = mkbase[5 + k];
    }

    unsigned pk = 0;
    float psc = 0.0f;

    // ---- one Viterbi step (compile-time k => literal buf, literal lanes) ----
    auto step = [&](int k, float lg, float mk) {
        const int buf = k & 1;
        // phase 1: gather own slice via LITERAL-lane readlanes
        float v[16];
        #pragma unroll
        for (int j = 0; j < 16; ++j)
            v[j] = rlf(fv, j) + tr[j];

        // carry-index ordered tree, depth 4 (strict >, left keeps ties)
        float mv[8]; int mi[8];
        #pragma unroll
        for (int c = 0; c < 8; ++c) {
            bool g = v[2 * c + 1] > v[2 * c];
            mv[c] = g ? v[2 * c + 1] : v[2 * c];
            mi[c] = g ? (2 * c + 1) : (2 * c);
        }
        #pragma unroll
        for (int st = 1; st < 8; st <<= 1) {
            #pragma unroll
            for (int c = 0; c < 8; c += 2 * st) {
                bool g = mv[c + st] > mv[c];
                mv[c] = g ? mv[c + st] : mv[c];
                mi[c] = g ? mi[c + st] : mi[c];
            }
        }
        pval[buf][w][tg] = mv[0];
        pidx[buf][w][tg] = pb + mi[0];

        lds_barrier();                   // lgkmcnt-only wait + s_barrier

        // phase 2: merge 4 partials for tag tg (ascending q, left-on-tie)
        float c0 = pval[buf][0][tg], c1 = pval[buf][1][tg];
        float c2 = pval[buf][2][tg], c3 = pval[buf][3][tg];
        int   j0 = pidx[buf][0][tg], j1 = pidx[buf][1][tg];
        int   j2 = pidx[buf][2][tg], j3 = pidx[buf][3][tg];
        bool g1 = c1 > c0;  float m01 = g1 ? c1 : c0;  int k01 = g1 ? j1 : j0;
        bool g3 = c3 > c2;  float m23 = g3 ? c3 : c2;  int k23 = g3 ? j3 : j2;
        bool gm = m23 > m01;
        float m  = gm ? m23 : m01;
        int   gi = gm ? k23 : k01;

        pk |= ((unsigned)gi) << (8 * k);     // wave0: tg==n, others harmless
        fv = m + lg * mk;                    // mask multiplies emission only
        return m;                            // pre-feat max (for path_score)
    };

    // main: groups g = 0..126 cover steps i = 4g+k (i <= 507)
    for (int g = 0; g < 127; ++g) {
        step(0, lgc[0], mkc[0]);
        step(1, lgc[1], mkc[1]);
        step(2, lgc[2], mkc[2]);
        step(3, lgc[3], mkc[3]);

        if (w == 0) bp[g * 64 + n] = pk;     // identity space: tg == n
        pk = 0;

        // rotate prefetch; issue loads for group g+2 (rows 4g+9 .. 4g+12)
        #pragma unroll
        for (int k = 0; k < 4; ++k) { lgc[k] = lgn[k]; mkc[k] = mkn[k]; }
        #pragma unroll
        for (int k = 0; k < 4; ++k) {
            int t = 4 * g + 9 + k;
            t = (t < Tz) ? t : (Tz - 1);
            lgn[k] = lgbase[t * Sz + tg];
            mkn[k] = mkbase[t];
        }
    }

    // tail: steps 508, 509, 510 (group 127, k = 0..2)
    step(0, lgc[0], mkc[0]);
    step(1, lgc[1], mkc[1]);
    float mlast = step(2, lgc[2], mkc[2]);
    psc = mlast;                             // vmaxs[-1] pre-feat

    if (w == 0) {
        bp[127 * 64 + n] = pk;               // flush steps 508..510
        if (n == 63) out[b] = psc;           // path_score = vmaxs[-1][:,63]
    }
    __syncthreads();

    // ---- backtrace (wave 0 only; validated readlane chain) ----
    if (w == 0) {
        unsigned wcur = bp[127 * 64 + n];
        int w127_63 = __builtin_amdgcn_readlane((int)wcur, 63);
        int tag = (w127_63 >> 16) & 255;     // t0 = bptrs[510][63]

        for (int g = 127; g >= 0; --g) {
            unsigned wnext = (g > 0) ? bp[(g - 1) * 64 + n] : 0u;  // prefetch
            int smax = (g == 127) ? 2 : 3;
            for (int s = smax; s >= 0; --s) {
                int idx = 4 * g + s;
                if (n == 0) ys[idx] = (float)tag;   // emit BEFORE following ptr
                int wd = __builtin_amdgcn_readlane((int)wcur, tag);
                tag = (wd >> (8 * s)) & 255;
            }
            wcur = wnext;
        }
    }
    __syncthreads();

    float* outseq = out + Bz + (size_t)b * (Tz - 1);
    for (int k = threadIdx.x; k < Tz - 1; k += 256) outseq[k] = ys[k];
}

extern "C" void kernel_launch(void* const* d_in, const int* in_sizes, int n_in,
                              void* d_out, int out_size, void* d_ws, size_t ws_size,
                              hipStream_t stream) {
    const float* logits = (const float*)d_in[0];
    const float* masks  = (const float*)d_in[1];
    const float* trans  = (const float*)d_in[2];
    float* out = (float*)d_out;
    (void)in_sizes; (void)n_in; (void)out_size; (void)d_ws; (void)ws_size;

    crf_viterbi_kernel<<<dim3(Bz), dim3(256), 0, stream>>>(logits, masks, trans, out);
}